// Round 8
// baseline (940.465 us; speedup 1.0000x reference)
//
#include <hip/hip_runtime.h>

// RWKV-7 Tmix (B=4, T=1024, C=1024, H=16, HS=64, H_KV=4)
// Round 7: wkv7 -> global_load_lds depth-8 pipeline (DMA queue, not VGPRs),
// counted vmcnt + raw s_barrier (no full drain), XCD-grouped block swizzle.
// GEMMs/fuse kernels unchanged from R6.

#define NROWS 4096      // B*T
#define CCH   1024
#define EPSV  0.00064f

typedef __attribute__((ext_vector_type(4))) float f32x4;
typedef __attribute__((ext_vector_type(8))) short bf16x8;

__device__ __forceinline__ unsigned short f2b(float f) {
    unsigned x = __float_as_uint(f);
    return (unsigned short)((x + 0x7fffu + ((x >> 16) & 1u)) >> 16);
}
__device__ __forceinline__ float b2f(unsigned short u) {
    return __uint_as_float(((unsigned)u) << 16);
}

#define LDSTR 40

// ---------------------------------------------------------------------------
// Split-precision MFMA GEMM: C[M,N] = A[M,K]*B[N,K]^T (f32 in/out).
// A,B -> bf16 hi+lo; C += Ahi*Bhi + Ahi*Blo + Alo*Bhi.
// BM=BN=128, BK=32, 256 thr = 4 waves. TANH64: tanh() on output cols < 64.
// ---------------------------------------------------------------------------
template<bool TANH64>
__global__ __launch_bounds__(256) void gemm_split(
    const float* __restrict__ A, int lda, const float* __restrict__ B, int ldb,
    float* __restrict__ C, int ldc, int M, int N, int K)
{
    __shared__ __align__(16) unsigned short Ah[128 * LDSTR];
    __shared__ __align__(16) unsigned short Al[128 * LDSTR];
    __shared__ __align__(16) unsigned short Bh[128 * LDSTR];
    __shared__ __align__(16) unsigned short Bl[128 * LDSTR];
    const int t = threadIdx.x;
    const int wave = t >> 6, lane = t & 63;
    const int m0 = blockIdx.y * 128, n0 = blockIdx.x * 128;
    const int wm = (wave >> 1) * 64, wn = (wave & 1) * 64;
    const int fr = lane & 15, kq = lane >> 4;

    f32x4 acc[4][4];
    #pragma unroll
    for (int i = 0; i < 4; ++i)
        #pragma unroll
        for (int j = 0; j < 4; ++j)
            acc[i][j] = (f32x4){0.f, 0.f, 0.f, 0.f};

    const int srow = t >> 3;         // 0..31
    const int scol = (t & 7) * 4;    // 0,4,..,28

    for (int k0 = 0; k0 < K; k0 += 32) {
        #pragma unroll
        for (int p = 0; p < 4; ++p) {
            const int row = p * 32 + srow;
            {
                const float4 v = *reinterpret_cast<const float4*>(
                    A + (size_t)(m0 + row) * lda + k0 + scol);
                ushort4 h, l;
                h.x = f2b(v.x); l.x = f2b(v.x - b2f(h.x));
                h.y = f2b(v.y); l.y = f2b(v.y - b2f(h.y));
                h.z = f2b(v.z); l.z = f2b(v.z - b2f(h.z));
                h.w = f2b(v.w); l.w = f2b(v.w - b2f(h.w));
                *reinterpret_cast<ushort4*>(&Ah[row * LDSTR + scol]) = h;
                *reinterpret_cast<ushort4*>(&Al[row * LDSTR + scol]) = l;
            }
            {
                float4 v = make_float4(0.f, 0.f, 0.f, 0.f);
                if (n0 + row < N)
                    v = *reinterpret_cast<const float4*>(
                        B + (size_t)(n0 + row) * ldb + k0 + scol);
                ushort4 h, l;
                h.x = f2b(v.x); l.x = f2b(v.x - b2f(h.x));
                h.y = f2b(v.y); l.y = f2b(v.y - b2f(h.y));
                h.z = f2b(v.z); l.z = f2b(v.z - b2f(h.z));
                h.w = f2b(v.w); l.w = f2b(v.w - b2f(h.w));
                *reinterpret_cast<ushort4*>(&Bh[row * LDSTR + scol]) = h;
                *reinterpret_cast<ushort4*>(&Bl[row * LDSTR + scol]) = l;
            }
        }
        __syncthreads();

        bf16x8 ah[4], al[4], bh[4], bl[4];
        #pragma unroll
        for (int mi = 0; mi < 4; ++mi) {
            ah[mi] = *reinterpret_cast<const bf16x8*>(&Ah[(wm + mi * 16 + fr) * LDSTR + kq * 8]);
            al[mi] = *reinterpret_cast<const bf16x8*>(&Al[(wm + mi * 16 + fr) * LDSTR + kq * 8]);
        }
        #pragma unroll
        for (int ni = 0; ni < 4; ++ni) {
            bh[ni] = *reinterpret_cast<const bf16x8*>(&Bh[(wn + ni * 16 + fr) * LDSTR + kq * 8]);
            bl[ni] = *reinterpret_cast<const bf16x8*>(&Bl[(wn + ni * 16 + fr) * LDSTR + kq * 8]);
        }
        #pragma unroll
        for (int mi = 0; mi < 4; ++mi)
            #pragma unroll
            for (int ni = 0; ni < 4; ++ni) {
                acc[mi][ni] = __builtin_amdgcn_mfma_f32_16x16x32_bf16(
                    al[mi], bh[ni], acc[mi][ni], 0, 0, 0);
                acc[mi][ni] = __builtin_amdgcn_mfma_f32_16x16x32_bf16(
                    ah[mi], bl[ni], acc[mi][ni], 0, 0, 0);
                acc[mi][ni] = __builtin_amdgcn_mfma_f32_16x16x32_bf16(
                    ah[mi], bh[ni], acc[mi][ni], 0, 0, 0);
            }
        __syncthreads();
    }

    const int crow0 = m0 + wm + kq * 4;
    const int ccol0 = n0 + wn + fr;
    #pragma unroll
    for (int mi = 0; mi < 4; ++mi)
        #pragma unroll
        for (int ni = 0; ni < 4; ++ni) {
            const int col = ccol0 + ni * 16;
            if (col < N) {
                #pragma unroll
                for (int i = 0; i < 4; ++i) {
                    float v = acc[mi][ni][i];
                    if (TANH64 && col < 64) v = tanhf(v);
                    C[(size_t)(crow0 + mi * 16 + i) * ldc + col] = v;
                }
            }
        }
}

// ---------------------------------------------------------------------------
// Plain bf16 MFMA GEMM (output projection — no error amplification).
// ---------------------------------------------------------------------------
__global__ __launch_bounds__(256) void gemm_mfma(
    const float* __restrict__ A, const float* __restrict__ B,
    float* __restrict__ C, int M, int N, int K)
{
    __shared__ __align__(16) unsigned short Ah[128 * LDSTR];
    __shared__ __align__(16) unsigned short Bh[128 * LDSTR];
    const int t = threadIdx.x;
    const int wave = t >> 6, lane = t & 63;
    const int m0 = blockIdx.y * 128, n0 = blockIdx.x * 128;
    const int wm = (wave >> 1) * 64, wn = (wave & 1) * 64;
    const int fr = lane & 15, kq = lane >> 4;

    f32x4 acc[4][4];
    #pragma unroll
    for (int i = 0; i < 4; ++i)
        #pragma unroll
        for (int j = 0; j < 4; ++j)
            acc[i][j] = (f32x4){0.f, 0.f, 0.f, 0.f};

    const int srow = t >> 3;
    const int scol = (t & 7) * 4;

    for (int k0 = 0; k0 < 1024; k0 += 32) {
        #pragma unroll
        for (int p = 0; p < 4; ++p) {
            const int row = p * 32 + srow;
            const float4 av = *reinterpret_cast<const float4*>(
                A + (size_t)(m0 + row) * 1024 + k0 + scol);
            ushort4 a4;
            a4.x = f2b(av.x); a4.y = f2b(av.y); a4.z = f2b(av.z); a4.w = f2b(av.w);
            *reinterpret_cast<ushort4*>(&Ah[row * LDSTR + scol]) = a4;
            const float4 bv = *reinterpret_cast<const float4*>(
                B + (size_t)(n0 + row) * 1024 + k0 + scol);
            ushort4 b4;
            b4.x = f2b(bv.x); b4.y = f2b(bv.y); b4.z = f2b(bv.z); b4.w = f2b(bv.w);
            *reinterpret_cast<ushort4*>(&Bh[row * LDSTR + scol]) = b4;
        }
        __syncthreads();

        bf16x8 af[4], bfr[4];
        #pragma unroll
        for (int mi = 0; mi < 4; ++mi)
            af[mi] = *reinterpret_cast<const bf16x8*>(&Ah[(wm + mi * 16 + fr) * LDSTR + kq * 8]);
        #pragma unroll
        for (int ni = 0; ni < 4; ++ni)
            bfr[ni] = *reinterpret_cast<const bf16x8*>(&Bh[(wn + ni * 16 + fr) * LDSTR + kq * 8]);
        #pragma unroll
        for (int mi = 0; mi < 4; ++mi)
            #pragma unroll
            for (int ni = 0; ni < 4; ++ni)
                acc[mi][ni] = __builtin_amdgcn_mfma_f32_16x16x32_bf16(
                    af[mi], bfr[ni], acc[mi][ni], 0, 0, 0);
        __syncthreads();
    }

    const int crow0 = m0 + wm + kq * 4;
    const int ccol0 = n0 + wn + fr;
    #pragma unroll
    for (int mi = 0; mi < 4; ++mi)
        #pragma unroll
        for (int ni = 0; ni < 4; ++ni) {
            const int col = ccol0 + ni * 16;
            #pragma unroll
            for (int i = 0; i < 4; ++i)
                C[(size_t)(crow0 + mi * 16 + i) * 1024 + col] = acc[mi][ni][i];
        }
}

// ---------------------------------------------------------------------------
// Weight packing: Wkv[512][1024] = [Wk;Wv];  Whid[160][1024] = [w1|a1|v1]^T;
// w2T[1024][64], a2T[1024][64], v2T[1024][32] transposes.
// ---------------------------------------------------------------------------
__global__ __launch_bounds__(256) void pack_all(
    const float* __restrict__ Wk, const float* __restrict__ Wv,
    const float* __restrict__ w1, const float* __restrict__ a1,
    const float* __restrict__ v1, const float* __restrict__ w2,
    const float* __restrict__ a2, const float* __restrict__ v2,
    float* __restrict__ Wkv, float* __restrict__ Whid,
    float* __restrict__ w2T, float* __restrict__ a2T, float* __restrict__ v2T)
{
    const int blk = blockIdx.x, t = threadIdx.x;
    if (blk < 512) {
        const float* s = blk < 256 ? Wk + (size_t)blk * 1024
                                   : Wv + (size_t)(blk - 256) * 1024;
        const float4 v = *reinterpret_cast<const float4*>(s + t * 4);
        *reinterpret_cast<float4*>(Wkv + (size_t)blk * 1024 + t * 4) = v;
    } else if (blk < 672) {
        const int f = blk - 512;     // 0..159
        for (int c = t; c < 1024; c += 256) {
            float val;
            if (f < 64)       val = w1[c * 64 + f];
            else if (f < 128) val = a1[c * 64 + (f - 64)];
            else              val = v1[c * 32 + (f - 128)];
            Whid[f * 1024 + c] = val;
        }
    } else {
        const int c = blk - 672;     // 0..1023
        if (t < 64)       w2T[c * 64 + t]         = w2[t * 1024 + c];
        else if (t < 128) a2T[c * 64 + (t - 64)]  = a2[(t - 64) * 1024 + c];
        else if (t < 160) v2T[c * 32 + (t - 128)] = v2[(t - 128) * 1024 + c];
    }
}

// ---------------------------------------------------------------------------
// Slim fuse_pre: dd/aacc/vacc come precomputed (GEMM) in buffers that ALIAS
// wdec/kf/vf (read idx then write idx — safe).
// ---------------------------------------------------------------------------
__global__ __launch_bounds__(256) void fuse_pre(
    const float* __restrict__ kv,
    const float* __restrict__ v_first, const float* __restrict__ mask,
    const float* __restrict__ w0, const float* __restrict__ a0,
    const float* __restrict__ v0,
    const float* __restrict__ k_k, const float* __restrict__ k_a,
    float* __restrict__ wdec, float* __restrict__ kf, float* __restrict__ vf,
    float* __restrict__ aab, float* __restrict__ bbb)
{
    const int n = blockIdx.x, t = threadIdx.x;
    const float m = mask[n];
    const bool live = m > 0.f;

    #pragma unroll
    for (int q = 0; q < 4; ++q) {
        const int c = q * 256 + t;
        const size_t idx = (size_t)n * 1024 + c;
        const float dd   = w0[c] + wdec[idx];   // ddl
        const float aacc = a0[c] + kf[idx];     // aal
        const float vacc = v0[c] + vf[idx];     // vvl

        const float u  = -dd;
        const float sp = fmaxf(u, 0.f) + log1pf(expf(-fabsf(u)));
        const float dec = expf(-expf(-sp - 0.6f));
        const float av = 1.f / (1.f + expf(-aacc));
        const float sv = 1.f / (1.f + expf(-vacc));

        const int  ck  = q * 64 + (c & 63);
        const float kr = kv[(size_t)n * 512 + ck];
        const float vr = kv[(size_t)n * 512 + 256 + ck];
        const float vfi = v_first[idx];
        const float vv  = vr + (vfi - vr) * sv;

        const float tkk = kr * k_k[c];
        float ss = tkk * tkk;
        #pragma unroll
        for (int off = 32; off > 0; off >>= 1) ss += __shfl_xor(ss, off, 64);
        const float kkv = tkk / fmaxf(sqrtf(ss), 1e-12f);

        wdec[idx] = live ? dec : 1.f;
        kf[idx]   = kr * (1.f + (av - 1.f) * k_a[c]) * m;
        vf[idx]   = vv * m;
        aab[idx]  = -kkv * m;
        bbb[idx]  = kkv * av * m;
    }
}

// ---------------------------------------------------------------------------
// WKV7 recurrence, global_load_lds depth-8 pipeline.
// 512 blocks x 2 waves. Block = (bh, row-octet): rows 8u..8u+7.
// Wave w: rows 8u+4w+(lane>>4); lane owns 4 channels c0=4*(lane&15).
// LDS: 9 slots x 6 arrays x 64 f32. Stage: wave0={wdec,aab,r}, wave1={kf,bbb,vf}.
// Per iter: issue stage(t+8) -> ds_read slot t -> compute -> y store ->
//           counted vmcnt -> raw s_barrier (no drain).
// Block swizzle groups all 8 blocks of a bh on one XCD.
// ---------------------------------------------------------------------------
__device__ __forceinline__ float qred16(float x) {
    x += __int_as_float(__builtin_amdgcn_update_dpp(
        0, __float_as_int(x), 0xB1, 0xF, 0xF, true));   // quad_perm xor1
    x += __int_as_float(__builtin_amdgcn_update_dpp(
        0, __float_as_int(x), 0x4E, 0xF, 0xF, true));   // quad_perm xor2
    x += __int_as_float(__builtin_amdgcn_update_dpp(
        0, __float_as_int(x), 0x141, 0xF, 0xF, true));  // row_half_mirror
    x += __int_as_float(__builtin_amdgcn_update_dpp(
        0, __float_as_int(x), 0x140, 0xF, 0xF, true));  // row_mirror
    return x;
}

__global__ __launch_bounds__(128) void wkv7(
    const float* __restrict__ r, const float* __restrict__ wdec,
    const float* __restrict__ kf, const float* __restrict__ vf,
    const float* __restrict__ aab, const float* __restrict__ bbb,
    float* __restrict__ y)
{
    __shared__ __align__(16) float sl[9][6][64];
    const int blk = blockIdx.x;                 // 0..511
    const int m  = blk & 7, q = blk >> 3;
    const int u  = q & 7, gq = q >> 3;
    const int bh = (gq << 3) | m;               // all 8 u-blocks of bh share m -> same XCD
    const int b = bh >> 4, h = bh & 15;
    const int wave = threadIdx.x >> 6;
    const int lane = threadIdx.x & 63;
    const int li   = lane & 15;
    const int i    = u * 8 + wave * 4 + (lane >> 4);   // value row 0..63
    const int c0   = li * 4;
    const size_t cb = (size_t)b * (1024 * 1024) + (size_t)h * 64;

#define GLL(g, l) __builtin_amdgcn_global_load_lds( \
        (const __attribute__((address_space(1))) unsigned int*)(g), \
        (__attribute__((address_space(3))) unsigned int*)(l), 4, 0, 0)

    // prologue: stage steps 0..7 (3 issues/wave/step -> 24 outstanding)
    for (int s = 0; s < 8; ++s) {
        const size_t p = cb + (size_t)s * 1024 + lane;
        if (wave == 0) {
            GLL(wdec + p, &sl[s][0][0]);
            GLL(aab  + p, &sl[s][2][0]);
            GLL(r    + p, &sl[s][4][0]);
        } else {
            GLL(kf   + p, &sl[s][1][0]);
            GLL(bbb  + p, &sl[s][3][0]);
            GLL(vf   + p, &sl[s][5][0]);
        }
    }
    asm volatile("s_waitcnt vmcnt(21)");        // slot 0's 3 loads retired
    __builtin_amdgcn_sched_barrier(0);
    __builtin_amdgcn_s_barrier();
    __builtin_amdgcn_sched_barrier(0);

    float4 S = make_float4(0.f, 0.f, 0.f, 0.f);

    for (int t = 0; t < 1024; ++t) {
        const int slot  = t % 9;
        const int wslot = (t + 8) % 9;
        const int tt    = t + 8 < 1024 ? t + 8 : 1023;   // tail: dummy re-stage
        const size_t pw = cb + (size_t)tt * 1024 + lane;
        if (wave == 0) {
            GLL(wdec + pw, &sl[wslot][0][0]);
            GLL(aab  + pw, &sl[wslot][2][0]);
            GLL(r    + pw, &sl[wslot][4][0]);
        } else {
            GLL(kf   + pw, &sl[wslot][1][0]);
            GLL(bbb  + pw, &sl[wslot][3][0]);
            GLL(vf   + pw, &sl[wslot][5][0]);
        }

        const float4 d4 = *reinterpret_cast<const float4*>(&sl[slot][0][c0]);
        const float4 k4 = *reinterpret_cast<const float4*>(&sl[slot][1][c0]);
        const float4 a4 = *reinterpret_cast<const float4*>(&sl[slot][2][c0]);
        const float4 b4 = *reinterpret_cast<const float4*>(&sl[slot][3][c0]);
        const float4 r4 = *reinterpret_cast<const float4*>(&sl[slot][4][c0]);
        const float vv  = sl[slot][5][i];

        float sa = S.x * a4.x + S.y * a4.y + S.z * a4.z + S.w * a4.w;
        sa = qred16(sa);
        S.x = S.x * d4.x + sa * b4.x + vv * k4.x;
        S.y = S.y * d4.y + sa * b4.y + vv * k4.y;
        S.z = S.z * d4.z + sa * b4.z + vv * k4.z;
        S.w = S.w * d4.w + sa * b4.w + vv * k4.w;
        float yv = S.x * r4.x + S.y * r4.y + S.z * r4.z + S.w * r4.w;
        yv = qred16(yv);
        if (li == 0) y[cb + (size_t)t * 1024 + i] = yv;

        // wait: stage(t+1) complete. outstanding = 7 slots x 3 loads (+<=8 y stores)
        if (t < 8) { asm volatile("s_waitcnt vmcnt(21)"); }
        else       { asm volatile("s_waitcnt vmcnt(29)"); }
        __builtin_amdgcn_sched_barrier(0);
        __builtin_amdgcn_s_barrier();
        __builtin_amdgcn_sched_barrier(0);
    }
#undef GLL
}

// ---------------------------------------------------------------------------
// Post: groupnorm per (row, head) + rk*v residual
// ---------------------------------------------------------------------------
__global__ __launch_bounds__(256) void fuse_post(
    const float* __restrict__ y, const float* __restrict__ r,
    const float* __restrict__ kf, const float* __restrict__ vf,
    const float* __restrict__ r_k, const float* __restrict__ ln_g, const float* __restrict__ ln_b,
    float* __restrict__ yn)
{
    const int n = blockIdx.x, t = threadIdx.x;
    #pragma unroll
    for (int q = 0; q < 4; ++q) {
        const int c = q * 256 + t;
        const size_t idx = (size_t)n * 1024 + c;
        const float yv = y[idx];
        float s1 = yv, s2 = yv * yv;
        float rk = r[idx] * kf[idx] * r_k[c];
        #pragma unroll
        for (int off = 32; off > 0; off >>= 1) {
            s1 += __shfl_xor(s1, off, 64);
            s2 += __shfl_xor(s2, off, 64);
            rk += __shfl_xor(rk, off, 64);
        }
        const float mu  = s1 * (1.f / 64.f);
        const float var = s2 * (1.f / 64.f) - mu * mu;
        yn[idx] = (yv - mu) * rsqrtf(var + EPSV) * ln_g[c] + ln_b[c]
                  + rk * vf[idx];
    }
}

// ---------------------------------------------------------------------------
extern "C" void kernel_launch(void* const* d_in, const int* in_sizes, int n_in,
                              void* d_out, int out_size, void* d_ws, size_t ws_size,
                              hipStream_t stream)
{
    const float* x       = (const float*)d_in[0];
    const float* v_first = (const float*)d_in[1];
    const float* mask    = (const float*)d_in[2];
    const float* Wr      = (const float*)d_in[3];
    const float* Wk      = (const float*)d_in[4];
    const float* Wv      = (const float*)d_in[5];
    const float* Wo      = (const float*)d_in[6];
    const float* w0      = (const float*)d_in[7];
    const float* w1      = (const float*)d_in[8];
    const float* w2      = (const float*)d_in[9];
    const float* a0      = (const float*)d_in[10];
    const float* a1      = (const float*)d_in[11];
    const float* a2      = (const float*)d_in[12];
    const float* v0      = (const float*)d_in[13];
    const float* v1      = (const float*)d_in[14];
    const float* v2      = (const float*)d_in[15];
    const float* k_k     = (const float*)d_in[16];
    const float* k_a     = (const float*)d_in[17];
    const float* r_k     = (const float*)d_in[18];
    const float* ln_g    = (const float*)d_in[19];
    const float* ln_b    = (const float*)d_in[20];
    float* out = (float*)d_out;

    float* ws = (float*)d_ws;
    const size_t M4 = (size_t)NROWS * CCH;   // 4M elements
    float* rbuf = ws;
    float* wdec = ws + 1 * M4;   // pre-fuse_pre: ddl
    float* kf   = ws + 2 * M4;   // pre-fuse_pre: aal
    float* vf   = ws + 3 * M4;   // pre-fuse_pre: vvl
    float* aab  = ws + 4 * M4;   // post-wkv7: yn
    float* bbb  = ws + 5 * M4;
    float* ybuf = ws + 6 * M4;
    // region-6 temps (dead before wkv7 writes ybuf):
    float* kv   = ybuf;                          // [4096][512]
    float* hid  = kv   + (size_t)NROWS * 512;    // [4096][160]
    float* Wkv  = hid  + (size_t)NROWS * 160;    // [512][1024]
    float* Whid = Wkv  + (size_t)512 * 1024;     // [160][1024]
    float* w2T  = Whid + (size_t)160 * 1024;     // [1024][64]
    float* a2T  = w2T  + (size_t)1024 * 64;      // [1024][64]
    float* v2T  = a2T  + (size_t)1024 * 64;      // [1024][32]
    float* yn = aab;

    dim3 blk(256);
    pack_all<<<1696, blk, 0, stream>>>(Wk, Wv, w1, a1, v1, w2, a2, v2,
                                       Wkv, Whid, w2T, a2T, v2T);
    gemm_split<false><<<dim3(8, 32), blk, 0, stream>>>(
        x, 1024, Wr, 1024, rbuf, 1024, NROWS, 1024, 1024);
    gemm_split<false><<<dim3(4, 32), blk, 0, stream>>>(
        x, 1024, Wkv, 1024, kv, 512, NROWS, 512, 1024);
    gemm_split<true><<<dim3(2, 32), blk, 0, stream>>>(
        x, 1024, Whid, 1024, hid, 160, NROWS, 160, 1024);
    // stage-2: dd -> wdec(ddl), aa -> kf(aal), vv -> vf(vvl)
    gemm_split<false><<<dim3(8, 32), blk, 0, stream>>>(
        hid, 160, w2T, 64, wdec, 1024, NROWS, 1024, 64);
    gemm_split<false><<<dim3(8, 32), blk, 0, stream>>>(
        hid + 64, 160, a2T, 64, kf, 1024, NROWS, 1024, 64);
    gemm_split<false><<<dim3(8, 32), blk, 0, stream>>>(
        hid + 128, 160, v2T, 32, vf, 1024, NROWS, 1024, 32);
    fuse_pre<<<NROWS, blk, 0, stream>>>(kv, v_first, mask, w0, a0, v0,
                                        k_k, k_a, wdec, kf, vf, aab, bbb);
    wkv7<<<512, dim3(128), 0, stream>>>(rbuf, wdec, kf, vf, aab, bbb, ybuf);
    fuse_post<<<NROWS, blk, 0, stream>>>(ybuf, rbuf, kf, vf, r_k, ln_g, ln_b, yn);
    gemm_mfma<<<dim3(8, 32), blk, 0, stream>>>(yn, Wo, out, NROWS, 1024, 1024);
    hipMemcpyAsync(out + M4, v_first, M4 * sizeof(float),
                   hipMemcpyDeviceToDevice, stream);
}

// Round 9
// 604.233 us; speedup vs baseline: 1.5565x; 1.5565x over previous
//
#include <hip/hip_runtime.h>

// RWKV-7 Tmix (B=4, T=1024, C=1024, H=16, HS=64, H_KV=4)
// Round 8: wkv7 = R6 structure (4 rows/wave, DPP reduces, register prefetch)
// with depth-2 prefetch (no VGPR spill of the queue) + XCD-grouping block
// swizzle (R7's FETCH win). kv+hid GEMMs merged into one N=672 GEMM.

#define NROWS 4096      // B*T
#define CCH   1024
#define EPSV  0.00064f

typedef __attribute__((ext_vector_type(4))) float f32x4;
typedef __attribute__((ext_vector_type(8))) short bf16x8;

__device__ __forceinline__ unsigned short f2b(float f) {
    unsigned x = __float_as_uint(f);
    return (unsigned short)((x + 0x7fffu + ((x >> 16) & 1u)) >> 16);
}
__device__ __forceinline__ float b2f(unsigned short u) {
    return __uint_as_float(((unsigned)u) << 16);
}

#define LDSTR 40

// ---------------------------------------------------------------------------
// Split-precision MFMA GEMM: C[M,N] = A[M,K]*B[N,K]^T (f32 in/out).
// A,B -> bf16 hi+lo; C += Ahi*Bhi + Ahi*Blo + Alo*Bhi.
// BM=BN=128, BK=32, 256 thr = 4 waves. TANH: tanh() on cols in [tl,th).
// ---------------------------------------------------------------------------
template<bool TANH>
__global__ __launch_bounds__(256) void gemm_split(
    const float* __restrict__ A, int lda, const float* __restrict__ B, int ldb,
    float* __restrict__ C, int ldc, int M, int N, int K, int tl, int th)
{
    __shared__ __align__(16) unsigned short Ah[128 * LDSTR];
    __shared__ __align__(16) unsigned short Al[128 * LDSTR];
    __shared__ __align__(16) unsigned short Bh[128 * LDSTR];
    __shared__ __align__(16) unsigned short Bl[128 * LDSTR];
    const int t = threadIdx.x;
    const int wave = t >> 6, lane = t & 63;
    const int m0 = blockIdx.y * 128, n0 = blockIdx.x * 128;
    const int wm = (wave >> 1) * 64, wn = (wave & 1) * 64;
    const int fr = lane & 15, kq = lane >> 4;

    f32x4 acc[4][4];
    #pragma unroll
    for (int i = 0; i < 4; ++i)
        #pragma unroll
        for (int j = 0; j < 4; ++j)
            acc[i][j] = (f32x4){0.f, 0.f, 0.f, 0.f};

    const int srow = t >> 3;         // 0..31
    const int scol = (t & 7) * 4;    // 0,4,..,28

    for (int k0 = 0; k0 < K; k0 += 32) {
        #pragma unroll
        for (int p = 0; p < 4; ++p) {
            const int row = p * 32 + srow;
            {
                const float4 v = *reinterpret_cast<const float4*>(
                    A + (size_t)(m0 + row) * lda + k0 + scol);
                ushort4 h, l;
                h.x = f2b(v.x); l.x = f2b(v.x - b2f(h.x));
                h.y = f2b(v.y); l.y = f2b(v.y - b2f(h.y));
                h.z = f2b(v.z); l.z = f2b(v.z - b2f(h.z));
                h.w = f2b(v.w); l.w = f2b(v.w - b2f(h.w));
                *reinterpret_cast<ushort4*>(&Ah[row * LDSTR + scol]) = h;
                *reinterpret_cast<ushort4*>(&Al[row * LDSTR + scol]) = l;
            }
            {
                float4 v = make_float4(0.f, 0.f, 0.f, 0.f);
                if (n0 + row < N)
                    v = *reinterpret_cast<const float4*>(
                        B + (size_t)(n0 + row) * ldb + k0 + scol);
                ushort4 h, l;
                h.x = f2b(v.x); l.x = f2b(v.x - b2f(h.x));
                h.y = f2b(v.y); l.y = f2b(v.y - b2f(h.y));
                h.z = f2b(v.z); l.z = f2b(v.z - b2f(h.z));
                h.w = f2b(v.w); l.w = f2b(v.w - b2f(h.w));
                *reinterpret_cast<ushort4*>(&Bh[row * LDSTR + scol]) = h;
                *reinterpret_cast<ushort4*>(&Bl[row * LDSTR + scol]) = l;
            }
        }
        __syncthreads();

        bf16x8 ah[4], al[4], bh[4], bl[4];
        #pragma unroll
        for (int mi = 0; mi < 4; ++mi) {
            ah[mi] = *reinterpret_cast<const bf16x8*>(&Ah[(wm + mi * 16 + fr) * LDSTR + kq * 8]);
            al[mi] = *reinterpret_cast<const bf16x8*>(&Al[(wm + mi * 16 + fr) * LDSTR + kq * 8]);
        }
        #pragma unroll
        for (int ni = 0; ni < 4; ++ni) {
            bh[ni] = *reinterpret_cast<const bf16x8*>(&Bh[(wn + ni * 16 + fr) * LDSTR + kq * 8]);
            bl[ni] = *reinterpret_cast<const bf16x8*>(&Bl[(wn + ni * 16 + fr) * LDSTR + kq * 8]);
        }
        #pragma unroll
        for (int mi = 0; mi < 4; ++mi)
            #pragma unroll
            for (int ni = 0; ni < 4; ++ni) {
                acc[mi][ni] = __builtin_amdgcn_mfma_f32_16x16x32_bf16(
                    al[mi], bh[ni], acc[mi][ni], 0, 0, 0);
                acc[mi][ni] = __builtin_amdgcn_mfma_f32_16x16x32_bf16(
                    ah[mi], bl[ni], acc[mi][ni], 0, 0, 0);
                acc[mi][ni] = __builtin_amdgcn_mfma_f32_16x16x32_bf16(
                    ah[mi], bh[ni], acc[mi][ni], 0, 0, 0);
            }
        __syncthreads();
    }

    const int crow0 = m0 + wm + kq * 4;
    const int ccol0 = n0 + wn + fr;
    #pragma unroll
    for (int mi = 0; mi < 4; ++mi)
        #pragma unroll
        for (int ni = 0; ni < 4; ++ni) {
            const int col = ccol0 + ni * 16;
            if (col < N) {
                #pragma unroll
                for (int i = 0; i < 4; ++i) {
                    float v = acc[mi][ni][i];
                    if (TANH && col >= tl && col < th) v = tanhf(v);
                    C[(size_t)(crow0 + mi * 16 + i) * ldc + col] = v;
                }
            }
        }
}

// ---------------------------------------------------------------------------
// Plain bf16 MFMA GEMM (output projection — no error amplification).
// ---------------------------------------------------------------------------
__global__ __launch_bounds__(256) void gemm_mfma(
    const float* __restrict__ A, const float* __restrict__ B,
    float* __restrict__ C, int M, int N, int K)
{
    __shared__ __align__(16) unsigned short Ah[128 * LDSTR];
    __shared__ __align__(16) unsigned short Bh[128 * LDSTR];
    const int t = threadIdx.x;
    const int wave = t >> 6, lane = t & 63;
    const int m0 = blockIdx.y * 128, n0 = blockIdx.x * 128;
    const int wm = (wave >> 1) * 64, wn = (wave & 1) * 64;
    const int fr = lane & 15, kq = lane >> 4;

    f32x4 acc[4][4];
    #pragma unroll
    for (int i = 0; i < 4; ++i)
        #pragma unroll
        for (int j = 0; j < 4; ++j)
            acc[i][j] = (f32x4){0.f, 0.f, 0.f, 0.f};

    const int srow = t >> 3;
    const int scol = (t & 7) * 4;

    for (int k0 = 0; k0 < 1024; k0 += 32) {
        #pragma unroll
        for (int p = 0; p < 4; ++p) {
            const int row = p * 32 + srow;
            const float4 av = *reinterpret_cast<const float4*>(
                A + (size_t)(m0 + row) * 1024 + k0 + scol);
            ushort4 a4;
            a4.x = f2b(av.x); a4.y = f2b(av.y); a4.z = f2b(av.z); a4.w = f2b(av.w);
            *reinterpret_cast<ushort4*>(&Ah[row * LDSTR + scol]) = a4;
            const float4 bv = *reinterpret_cast<const float4*>(
                B + (size_t)(n0 + row) * 1024 + k0 + scol);
            ushort4 b4;
            b4.x = f2b(bv.x); b4.y = f2b(bv.y); b4.z = f2b(bv.z); b4.w = f2b(bv.w);
            *reinterpret_cast<ushort4*>(&Bh[row * LDSTR + scol]) = b4;
        }
        __syncthreads();

        bf16x8 af[4], bfr[4];
        #pragma unroll
        for (int mi = 0; mi < 4; ++mi)
            af[mi] = *reinterpret_cast<const bf16x8*>(&Ah[(wm + mi * 16 + fr) * LDSTR + kq * 8]);
        #pragma unroll
        for (int ni = 0; ni < 4; ++ni)
            bfr[ni] = *reinterpret_cast<const bf16x8*>(&Bh[(wn + ni * 16 + fr) * LDSTR + kq * 8]);
        #pragma unroll
        for (int mi = 0; mi < 4; ++mi)
            #pragma unroll
            for (int ni = 0; ni < 4; ++ni)
                acc[mi][ni] = __builtin_amdgcn_mfma_f32_16x16x32_bf16(
                    af[mi], bfr[ni], acc[mi][ni], 0, 0, 0);
        __syncthreads();
    }

    const int crow0 = m0 + wm + kq * 4;
    const int ccol0 = n0 + wn + fr;
    #pragma unroll
    for (int mi = 0; mi < 4; ++mi)
        #pragma unroll
        for (int ni = 0; ni < 4; ++ni) {
            const int col = ccol0 + ni * 16;
            #pragma unroll
            for (int i = 0; i < 4; ++i)
                C[(size_t)(crow0 + mi * 16 + i) * 1024 + col] = acc[mi][ni][i];
        }
}

// ---------------------------------------------------------------------------
// Weight packing: Wkvh[672][1024] = [Wk; Wv; w1^T; a1^T; v1^T];
// w2T[1024][64], a2T[1024][64], v2T[1024][32] transposes.
// ---------------------------------------------------------------------------
__global__ __launch_bounds__(256) void pack_all(
    const float* __restrict__ Wk, const float* __restrict__ Wv,
    const float* __restrict__ w1, const float* __restrict__ a1,
    const float* __restrict__ v1, const float* __restrict__ w2,
    const float* __restrict__ a2, const float* __restrict__ v2,
    float* __restrict__ Wkvh,
    float* __restrict__ w2T, float* __restrict__ a2T, float* __restrict__ v2T)
{
    const int blk = blockIdx.x, t = threadIdx.x;
    if (blk < 512) {
        const float* s = blk < 256 ? Wk + (size_t)blk * 1024
                                   : Wv + (size_t)(blk - 256) * 1024;
        const float4 v = *reinterpret_cast<const float4*>(s + t * 4);
        *reinterpret_cast<float4*>(Wkvh + (size_t)blk * 1024 + t * 4) = v;
    } else if (blk < 672) {
        const int f = blk - 512;     // 0..159
        for (int c = t; c < 1024; c += 256) {
            float val;
            if (f < 64)       val = w1[c * 64 + f];
            else if (f < 128) val = a1[c * 64 + (f - 64)];
            else              val = v1[c * 32 + (f - 128)];
            Wkvh[(size_t)(512 + f) * 1024 + c] = val;
        }
    } else {
        const int c = blk - 672;     // 0..1023
        if (t < 64)       w2T[c * 64 + t]         = w2[t * 1024 + c];
        else if (t < 128) a2T[c * 64 + (t - 64)]  = a2[(t - 64) * 1024 + c];
        else if (t < 160) v2T[c * 32 + (t - 128)] = v2[(t - 128) * 1024 + c];
    }
}

// ---------------------------------------------------------------------------
// Slim fuse_pre: dd/aacc/vacc precomputed (GEMM) in buffers that ALIAS
// wdec/kf/vf (read idx then write idx — safe). kvh row stride 672.
// ---------------------------------------------------------------------------
__global__ __launch_bounds__(256) void fuse_pre(
    const float* __restrict__ kvh,
    const float* __restrict__ v_first, const float* __restrict__ mask,
    const float* __restrict__ w0, const float* __restrict__ a0,
    const float* __restrict__ v0,
    const float* __restrict__ k_k, const float* __restrict__ k_a,
    float* __restrict__ wdec, float* __restrict__ kf, float* __restrict__ vf,
    float* __restrict__ aab, float* __restrict__ bbb)
{
    const int n = blockIdx.x, t = threadIdx.x;
    const float m = mask[n];
    const bool live = m > 0.f;

    #pragma unroll
    for (int q = 0; q < 4; ++q) {
        const int c = q * 256 + t;
        const size_t idx = (size_t)n * 1024 + c;
        const float dd   = w0[c] + wdec[idx];   // ddl
        const float aacc = a0[c] + kf[idx];     // aal
        const float vacc = v0[c] + vf[idx];     // vvl

        const float u  = -dd;
        const float sp = fmaxf(u, 0.f) + log1pf(expf(-fabsf(u)));
        const float dec = expf(-expf(-sp - 0.6f));
        const float av = 1.f / (1.f + expf(-aacc));
        const float sv = 1.f / (1.f + expf(-vacc));

        const int  ck  = q * 64 + (c & 63);
        const float kr = kvh[(size_t)n * 672 + ck];
        const float vr = kvh[(size_t)n * 672 + 256 + ck];
        const float vfi = v_first[idx];
        const float vv  = vr + (vfi - vr) * sv;

        const float tkk = kr * k_k[c];
        float ss = tkk * tkk;
        #pragma unroll
        for (int off = 32; off > 0; off >>= 1) ss += __shfl_xor(ss, off, 64);
        const float kkv = tkk / fmaxf(sqrtf(ss), 1e-12f);

        wdec[idx] = live ? dec : 1.f;
        kf[idx]   = kr * (1.f + (av - 1.f) * k_a[c]) * m;
        vf[idx]   = vv * m;
        aab[idx]  = -kkv * m;
        bbb[idx]  = kkv * av * m;
    }
}

// ---------------------------------------------------------------------------
// WKV7: 256 blocks x 4 waves; wave = (bh, 4 value-rows). 16 lanes/row,
// float4 channels, DPP-only reduces. Depth-2 register prefetch (42 VGPR
// queue — no spill). XCD swizzle: all 4 blocks of a bh share blk%8.
// ---------------------------------------------------------------------------
__device__ __forceinline__ float qred16(float x) {
    x += __int_as_float(__builtin_amdgcn_update_dpp(
        0, __float_as_int(x), 0xB1, 0xF, 0xF, true));   // quad_perm xor1
    x += __int_as_float(__builtin_amdgcn_update_dpp(
        0, __float_as_int(x), 0x4E, 0xF, 0xF, true));   // quad_perm xor2
    x += __int_as_float(__builtin_amdgcn_update_dpp(
        0, __float_as_int(x), 0x141, 0xF, 0xF, true));  // row_half_mirror
    x += __int_as_float(__builtin_amdgcn_update_dpp(
        0, __float_as_int(x), 0x140, 0xF, 0xF, true));  // row_mirror
    return x;
}

__global__ __launch_bounds__(256, 1) void wkv7(
    const float* __restrict__ r, const float* __restrict__ wdec,
    const float* __restrict__ kf, const float* __restrict__ vf,
    const float* __restrict__ aab, const float* __restrict__ bbb,
    float* __restrict__ y)
{
    const int blk = blockIdx.x;               // 0..255
    const int m  = blk & 7;
    const int s  = blk >> 3;                  // 0..31
    const int bh = (s >> 2) * 8 + m;          // all 4 blocks of bh share m -> same XCD
    const int j  = s & 3;
    const int b = bh >> 4, h = bh & 15;
    const int wave = threadIdx.x >> 6;
    const int lane = threadIdx.x & 63;
    const int li   = lane & 15;
    const int i    = j * 16 + wave * 4 + (lane >> 4);  // value row 0..63
    const int c0   = li * 4;
    const size_t cb = (size_t)b * (1024 * 1024) + (size_t)h * 64;

    float4 S = make_float4(0.f, 0.f, 0.f, 0.f);

    float4 dA, kA, aA, bA, rA; float vA;
    float4 dB, kB, aB, bB, rB; float vB;

#define LD(T, d_, k_, a_, b_, r_, v_)                                   \
    {   const size_t p_ = cb + (size_t)(T) * 1024;                      \
        d_ = *reinterpret_cast<const float4*>(wdec + p_ + c0);          \
        k_ = *reinterpret_cast<const float4*>(kf   + p_ + c0);          \
        a_ = *reinterpret_cast<const float4*>(aab  + p_ + c0);          \
        b_ = *reinterpret_cast<const float4*>(bbb  + p_ + c0);          \
        r_ = *reinterpret_cast<const float4*>(r    + p_ + c0);          \
        v_ = vf[p_ + i]; }

#define STEP(d_, k_, a_, b_, r_, v_, YOUT)                              \
    {   float sa_ = S.x * a_.x + S.y * a_.y + S.z * a_.z + S.w * a_.w;  \
        sa_ = qred16(sa_);                                              \
        S.x = S.x * d_.x + sa_ * b_.x + v_ * k_.x;                     \
        S.y = S.y * d_.y + sa_ * b_.y + v_ * k_.y;                     \
        S.z = S.z * d_.z + sa_ * b_.z + v_ * k_.z;                     \
        S.w = S.w * d_.w + sa_ * b_.w + v_ * k_.w;                     \
        float yv_ = S.x * r_.x + S.y * r_.y + S.z * r_.z + S.w * r_.w; \
        YOUT = qred16(yv_); }

    LD(0, dA, kA, aA, bA, rA, vA);
    LD(1, dB, kB, aB, bB, rB, vB);

    for (int t = 0; t < 1024; t += 2) {
        float y0, y1;
        const int t2 = t + 2 < 1024 ? t + 2 : 1023;
        const int t3 = t + 3 < 1024 ? t + 3 : 1023;
        STEP(dA, kA, aA, bA, rA, vA, y0);
        LD(t2, dA, kA, aA, bA, rA, vA);
        STEP(dB, kB, aB, bB, rB, vB, y1);
        LD(t3, dB, kB, aB, bB, rB, vB);
        if (li == 0) {
            const size_t yb = cb + (size_t)t * 1024 + i;
            y[yb]        = y0;
            y[yb + 1024] = y1;
        }
    }
#undef LD
#undef STEP
}

// ---------------------------------------------------------------------------
// Post: groupnorm per (row, head) + rk*v residual
// ---------------------------------------------------------------------------
__global__ __launch_bounds__(256) void fuse_post(
    const float* __restrict__ y, const float* __restrict__ r,
    const float* __restrict__ kf, const float* __restrict__ vf,
    const float* __restrict__ r_k, const float* __restrict__ ln_g, const float* __restrict__ ln_b,
    float* __restrict__ yn)
{
    const int n = blockIdx.x, t = threadIdx.x;
    #pragma unroll
    for (int q = 0; q < 4; ++q) {
        const int c = q * 256 + t;
        const size_t idx = (size_t)n * 1024 + c;
        const float yv = y[idx];
        float s1 = yv, s2 = yv * yv;
        float rk = r[idx] * kf[idx] * r_k[c];
        #pragma unroll
        for (int off = 32; off > 0; off >>= 1) {
            s1 += __shfl_xor(s1, off, 64);
            s2 += __shfl_xor(s2, off, 64);
            rk += __shfl_xor(rk, off, 64);
        }
        const float mu  = s1 * (1.f / 64.f);
        const float var = s2 * (1.f / 64.f) - mu * mu;
        yn[idx] = (yv - mu) * rsqrtf(var + EPSV) * ln_g[c] + ln_b[c]
                  + rk * vf[idx];
    }
}

// ---------------------------------------------------------------------------
extern "C" void kernel_launch(void* const* d_in, const int* in_sizes, int n_in,
                              void* d_out, int out_size, void* d_ws, size_t ws_size,
                              hipStream_t stream)
{
    const float* x       = (const float*)d_in[0];
    const float* v_first = (const float*)d_in[1];
    const float* mask    = (const float*)d_in[2];
    const float* Wr      = (const float*)d_in[3];
    const float* Wk      = (const float*)d_in[4];
    const float* Wv      = (const float*)d_in[5];
    const float* Wo      = (const float*)d_in[6];
    const float* w0      = (const float*)d_in[7];
    const float* w1      = (const float*)d_in[8];
    const float* w2      = (const float*)d_in[9];
    const float* a0      = (const float*)d_in[10];
    const float* a1      = (const float*)d_in[11];
    const float* a2      = (const float*)d_in[12];
    const float* v0      = (const float*)d_in[13];
    const float* v1      = (const float*)d_in[14];
    const float* v2      = (const float*)d_in[15];
    const float* k_k     = (const float*)d_in[16];
    const float* k_a     = (const float*)d_in[17];
    const float* r_k     = (const float*)d_in[18];
    const float* ln_g    = (const float*)d_in[19];
    const float* ln_b    = (const float*)d_in[20];
    float* out = (float*)d_out;

    float* ws = (float*)d_ws;
    const size_t M4 = (size_t)NROWS * CCH;   // 4M elements
    float* rbuf = ws;
    float* wdec = ws + 1 * M4;   // pre-fuse_pre: ddl
    float* kf   = ws + 2 * M4;   // pre-fuse_pre: aal
    float* vf   = ws + 3 * M4;   // pre-fuse_pre: vvl
    float* aab  = ws + 4 * M4;   // post-wkv7: yn
    float* bbb  = ws + 5 * M4;
    float* ybuf = ws + 6 * M4;
    // region-6 temps (dead before wkv7 writes ybuf):
    float* kvh  = ybuf;                          // [4096][672]
    float* w2T  = kvh  + (size_t)NROWS * 672;    // [1024][64]
    float* a2T  = w2T  + (size_t)1024 * 64;      // [1024][64]
    float* v2T  = a2T  + (size_t)1024 * 64;      // [1024][32]
    float* Wkvh = v2T  + (size_t)1024 * 32;      // [672][1024]
    float* yn = aab;

    dim3 blk(256);
    pack_all<<<1696, blk, 0, stream>>>(Wk, Wv, w1, a1, v1, w2, a2, v2,
                                       Wkvh, w2T, a2T, v2T);
    gemm_split<false><<<dim3(8, 32), blk, 0, stream>>>(
        x, 1024, Wr, 1024, rbuf, 1024, NROWS, 1024, 1024, 0, 0);
    gemm_split<true><<<dim3(6, 32), blk, 0, stream>>>(
        x, 1024, Wkvh, 1024, kvh, 672, NROWS, 672, 1024, 512, 576);
    // stage-2: dd -> wdec(ddl), aa -> kf(aal), vv -> vf(vvl)
    gemm_split<false><<<dim3(8, 32), blk, 0, stream>>>(
        kvh + 512, 672, w2T, 64, wdec, 1024, NROWS, 1024, 64, 0, 0);
    gemm_split<false><<<dim3(8, 32), blk, 0, stream>>>(
        kvh + 576, 672, a2T, 64, kf, 1024, NROWS, 1024, 64, 0, 0);
    gemm_split<false><<<dim3(8, 32), blk, 0, stream>>>(
        kvh + 640, 672, v2T, 32, vf, 1024, NROWS, 1024, 32, 0, 0);
    fuse_pre<<<NROWS, blk, 0, stream>>>(kvh, v_first, mask, w0, a0, v0,
                                        k_k, k_a, wdec, kf, vf, aab, bbb);
    wkv7<<<256, blk, 0, stream>>>(rbuf, wdec, kf, vf, aab, bbb, ybuf);
    fuse_post<<<NROWS, blk, 0, stream>>>(ybuf, rbuf, kf, vf, r_k, ln_g, ln_b, yn);
    gemm_mfma<<<dim3(8, 32), blk, 0, stream>>>(yn, Wo, out, NROWS, 1024, 1024);
    hipMemcpyAsync(out + M4, v_first, M4 * sizeof(float),
                   hipMemcpyDeviceToDevice, stream);
}